// Round 10
// baseline (797.308 us; speedup 1.0000x reference)
//
#include <hip/hip_runtime.h>
#include <hip/hip_bf16.h>
#include <math.h>

#define CDIM 512
#define NPIX 4096
#define BATCH 2
#define NGROUP 32
#define CPG 16
#define EPSV 1e-6f

#define QT 64
#define KT 64
#define KS 8
#define KEYS_PER (NPIX / KS)   // 512
#define NKT (KEYS_PER / KT)    // 8
#define NWIN (NKT * 8)         // 64 chunk-windows per block

typedef __attribute__((ext_vector_type(4))) float f32x4;
typedef _Float16 f16x8 __attribute__((ext_vector_type(8)));
typedef __attribute__((ext_vector_type(8))) unsigned short ushort8v;
typedef __attribute__((ext_vector_type(4))) unsigned short ushort4v;

__device__ inline unsigned short f2h(float x) {
  _Float16 h = (_Float16)x;
  return __builtin_bit_cast(unsigned short, h);
}
__device__ inline float h2f(unsigned short u) {
  return (float)__builtin_bit_cast(_Float16, u);
}

__device__ inline void gload_lds16(const void* g, void* l) {
  __builtin_amdgcn_global_load_lds((const __attribute__((address_space(1))) void*)g,
                                   (__attribute__((address_space(3))) void*)l, 16, 0, 0);
}

// ---------------- GroupNorm ----------------
__global__ __launch_bounds__(1024)
void gn_kernel(const float* __restrict__ x, const float* __restrict__ gamma,
               const float* __restrict__ beta, float* __restrict__ h) {
  const int NE = CPG * NPIX;
  int b = blockIdx.x >> 5;
  int g = blockIdx.x & 31;
  size_t base = ((size_t)b * CDIM + (size_t)g * CPG) * NPIX;
  const float4* xv = (const float4*)(x + base);
  float4* hv = (float4*)(h + base);
  int t = threadIdx.x;
  float s = 0.f, ss = 0.f;
  for (int i = t; i < NE / 4; i += 1024) {
    float4 v = xv[i];
    s += (v.x + v.y) + (v.z + v.w);
    ss += v.x * v.x + v.y * v.y + v.z * v.z + v.w * v.w;
  }
#pragma unroll
  for (int off = 32; off >= 1; off >>= 1) {
    s += __shfl_down(s, off);
    ss += __shfl_down(ss, off);
  }
  __shared__ float redS[16], redQ[16];
  int wid = t >> 6;
  if ((t & 63) == 0) { redS[wid] = s; redQ[wid] = ss; }
  __syncthreads();
  __shared__ float s_mu, s_rs;
  if (t == 0) {
    float S = 0.f, Q = 0.f;
    for (int w = 0; w < 16; ++w) { S += redS[w]; Q += redQ[w]; }
    float mu = S / NE;
    float var = Q / NE - mu * mu;
    s_mu = mu;
    s_rs = rsqrtf(var + EPSV);
  }
  __syncthreads();
  float mu = s_mu, rs = s_rs;
  for (int i = t; i < NE / 4; i += 1024) {
    int c = g * CPG + (i >> 10);
    float ga = gamma[c] * rs;
    float be = beta[c] - mu * ga;
    float4 v = xv[i];
    v.x = v.x * ga + be;
    v.y = v.y * ga + be;
    v.z = v.z * ga + be;
    v.w = v.w * ga + be;
    hv[i] = v;
  }
}

// ---------------- conv1x1 GEMM ----------------
// MODE 0: fp32 out + residual (proj). MODE 1: fp16 hi/lo TRANSPOSED out [b][n][c] (q,k).
// MODE 2: fp16 single out [b][c][n] (v).
#define BKc 16
#define WPAD 68

template <int MODE>
__global__ __launch_bounds__(256)
void conv1x1_kernel(const float* __restrict__ W, const float* __restrict__ bias,
                    const float* __restrict__ src, const float* __restrict__ resid,
                    float* __restrict__ dst, unsigned short* __restrict__ dsth,
                    unsigned short* __restrict__ dstl) {
  __shared__ __align__(16) float w_lds[BKc][WPAD];
  __shared__ __align__(16) float h_lds[BKc][64];
  __shared__ __align__(16) unsigned short t_lds[64][72];
  int t = threadIdx.x;
  int nBase = blockIdx.x * 64;
  int oBase = blockIdx.y * 64;
  int b = blockIdx.z;
  const float* srcb = src + (size_t)b * CDIM * NPIX;
  float acc[4][4] = {};
  int o0 = 4 * (t >> 4);
  int j0 = 4 * (t & 15);
  for (int c0 = 0; c0 < CDIM; c0 += BKc) {
    __syncthreads();
#pragma unroll
    for (int kk = 0; kk < 4; ++kk) {
      int idx = t + 256 * kk;
      int o_l = idx >> 4, c_l = idx & 15;
      w_lds[c_l][o_l] = W[(size_t)(oBase + o_l) * CDIM + c0 + c_l];
    }
#pragma unroll
    for (int kk = 0; kk < 4; ++kk) {
      int idx = t + 256 * kk;
      int c_l = idx >> 6, j = idx & 63;
      h_lds[c_l][j] = srcb[(size_t)(c0 + c_l) * NPIX + nBase + j];
    }
    __syncthreads();
#pragma unroll
    for (int kk = 0; kk < BKc; ++kk) {
      float4 a = *(const float4*)&w_lds[kk][o0];
      float4 bv = *(const float4*)&h_lds[kk][j0];
      float av[4] = {a.x, a.y, a.z, a.w};
      float bb[4] = {bv.x, bv.y, bv.z, bv.w};
#pragma unroll
      for (int r = 0; r < 4; ++r)
#pragma unroll
        for (int s2 = 0; s2 < 4; ++s2) acc[r][s2] += av[r] * bb[s2];
    }
  }
  if (MODE == 0) {
#pragma unroll
    for (int r = 0; r < 4; ++r) {
      int o = oBase + o0 + r;
      float bi = bias[o];
      size_t off = ((size_t)b * CDIM + o) * NPIX + nBase + j0;
      float4 out;
      out.x = acc[r][0] + bi;
      out.y = acc[r][1] + bi;
      out.z = acc[r][2] + bi;
      out.w = acc[r][3] + bi;
      float4 rv = *(const float4*)(resid + off);
      out.x += rv.x; out.y += rv.y; out.z += rv.z; out.w += rv.w;
      *(float4*)(dst + off) = out;
    }
  } else if (MODE == 2) {
#pragma unroll
    for (int r = 0; r < 4; ++r) {
      int o = oBase + o0 + r;
      float bi = bias[o];
      size_t off = ((size_t)b * CDIM + o) * NPIX + nBase + j0;
      ushort4v hv;
#pragma unroll
      for (int s2 = 0; s2 < 4; ++s2) hv[s2] = f2h(acc[r][s2] + bi);
      *(ushort4v*)(dsth + off) = hv;
    }
  } else {
    float biv[4];
#pragma unroll
    for (int r = 0; r < 4; ++r) biv[r] = bias[oBase + o0 + r];
#pragma unroll
    for (int phase = 0; phase < 2; ++phase) {
      __syncthreads();
#pragma unroll
      for (int r = 0; r < 4; ++r)
#pragma unroll
        for (int s2 = 0; s2 < 4; ++s2) {
          float val = acc[r][s2] + biv[r];
          unsigned short hu = f2h(val);
          t_lds[j0 + s2][o0 + r] = phase == 0 ? hu : f2h(val - h2f(hu));
        }
      __syncthreads();
      unsigned short* dp = phase == 0 ? dsth : dstl;
      int row = t >> 2, seg = t & 3;
      size_t goff = ((size_t)b * NPIX + nBase + row) * CDIM + oBase + seg * 16;
#pragma unroll
      for (int e = 0; e < 2; ++e)
        *(ushort8v*)(dp + goff + 8 * e) = *(ushort8v*)&t_lds[row][seg * 16 + 8 * e];
    }
  }
}

// ---------------- MFMA flash attention (fp16 split) ----------------
// 256 thr (4 waves). QT=64 rows, KT=64 keys/tile, KS=8 key-splits.
// Chunk-window stream: 64 windows (8 chunks x 8 kts), triple-buffered LDS,
// ONE barrier per window, depth-2 prefetch, vmcnt(4) steady-state (never 0 mid-stream).
// S: fp16 3-pass (QhKh+QlKh+QhKl). PV: fp16 single-pass (P fp16, V fp16), chan-split.
// Epilogue: opart[pair][chan][row] fp16 packed 4-row stores (full-line friendly).
// pair MUST equal b*KS+ks (wn/combine use that ordering) — R8 bug was pair=2ks+b.
__global__ __launch_bounds__(256, 2)
void attn_kernel(const unsigned short* __restrict__ qt_hi, const unsigned short* __restrict__ qt_lo,
                 const unsigned short* __restrict__ kt_hi, const unsigned short* __restrict__ kt_lo,
                 const unsigned short* __restrict__ vbuf,
                 unsigned short* __restrict__ opart, float* __restrict__ mlbuf) {
  __shared__ __align__(16) unsigned short ktile[3][2][64 * 64];  // [buf][hi/lo][key*64+slot]
  __shared__ __align__(16) unsigned short plds[64 * 72];         // P fp16 [row][key+pad]
  __shared__ float flds[64];

  int t = threadIdx.x;
  int lane = t & 63;
  int l15 = lane & 15;
  int hh = lane >> 4;
  int w = t >> 6;
  int bid = blockIdx.x;
  int pair = bid & 15;           // consecutive bids -> 16 distinct (b,ks) panels
  int b = pair >> 3;             // pair == b*KS + ks  (matches wn/combine ordering)
  int ks = pair & 7;
  int qtile = bid >> 4;
  int qBase = qtile * QT;

  const unsigned short* qh = qt_hi + ((size_t)b * NPIX + qBase) * CDIM;
  const unsigned short* ql = qt_lo + ((size_t)b * NPIX + qBase) * CDIM;
  const unsigned short* kh = kt_hi + ((size_t)b * NPIX + ks * KEYS_PER) * CDIM;
  const unsigned short* kl = kt_lo + ((size_t)b * NPIX + ks * KEYS_PER) * CDIM;
  const unsigned short* vb = vbuf + (size_t)b * CDIM * NPIX + ks * KEYS_PER;

  const unsigned short* qrow_h = qh + (size_t)(16 * w + l15) * CDIM + 8 * hh;
  const unsigned short* qrow_l = ql + (size_t)(16 * w + l15) * CDIM + 8 * hh;

  f32x4 Oacc[4][8];
#pragma unroll
  for (int rg = 0; rg < 4; ++rg)
#pragma unroll
    for (int cf = 0; cf < 8; ++cf) Oacc[rg][cf] = (f32x4){0.f, 0.f, 0.f, 0.f};
  float mrow[4], lrow[4];
#pragma unroll
  for (int r = 0; r < 4; ++r) { mrow[r] = -1e30f; lrow[r] = 0.f; }

  const float scale = 0.044194173824159216f;

  // issue chunk-window g (4 gload_lds16/thread): chunk = 64 keys x 64 chans hi+lo
  auto issue = [&](int g) {
    int ch = g & 7;
    int ktof = (g >> 3) * KT;
    int d = g % 3;
#pragma unroll
    for (int j = 0; j < 4; ++j) {
      int idx = w * 4 + j;
      int hl = idx >> 3;
      int sub = idx & 7;
      const unsigned short* src = hl ? kl : kh;
      int key = sub * 8 + (lane >> 3);
      int cb = (lane & 7) ^ ((lane >> 3) & 7);  // pre-swizzled source chan-block
      gload_lds16(src + (size_t)(ktof + key) * CDIM + ch * 64 + cb * 8,
                  &ktile[d][hl][sub * 512]);
    }
  };

  issue(0);
  issue(1);

  for (int kt = 0; kt < NKT; ++kt) {
    f32x4 Sacc[4];
#pragma unroll
    for (int f = 0; f < 4; ++f) Sacc[f] = (f32x4){0.f, 0.f, 0.f, 0.f};
    for (int ch = 0; ch < 8; ++ch) {
      int g = kt * 8 + ch;
      // window entry: chunk g must be resident. outstanding = g(4, old) + g+1(4, newer).
      if (g + 1 < NWIN) {
        asm volatile("s_waitcnt vmcnt(4)" ::: "memory");
      } else {
        asm volatile("s_waitcnt vmcnt(0)" ::: "memory");
      }
      __builtin_amdgcn_s_barrier();
      if (g + 2 < NWIN) issue(g + 2);  // writes buf (g+2)%3 == (g-1)%3: all waves past barrier g
      int d = g % 3;
#pragma unroll
      for (int sc = 0; sc < 2; ++sc) {
        int cc = ch * 2 + sc;
        f16x8 qfh_ = *(const f16x8*)(qrow_h + 32 * cc);
        f16x8 qfl_ = *(const f16x8*)(qrow_l + 32 * cc);
        int cbl = sc * 4 + hh;
#pragma unroll
        for (int f = 0; f < 4; ++f) {
          int key = 16 * f + l15;
          int swz = cbl ^ (key & 7);
          f16x8 bh = *(const f16x8*)&ktile[d][0][key * 64 + swz * 8];
          f16x8 bl = *(const f16x8*)&ktile[d][1][key * 64 + swz * 8];
          Sacc[f] = __builtin_amdgcn_mfma_f32_16x16x32_f16(qfh_, bh, Sacc[f], 0, 0, 0);
          Sacc[f] = __builtin_amdgcn_mfma_f32_16x16x32_f16(qfl_, bh, Sacc[f], 0, 0, 0);
          Sacc[f] = __builtin_amdgcn_mfma_f32_16x16x32_f16(qfh_, bl, Sacc[f], 0, 0, 0);
        }
      }
    }
    int ktof = kt * KT;
    // ---- online softmax (rows 16w..16w+15; keys of row live on 16 l15-lanes x 4 f-frags) ----
#pragma unroll
    for (int r = 0; r < 4; ++r) {
      float sv[4];
#pragma unroll
      for (int f = 0; f < 4; ++f) sv[f] = Sacc[f][r] * scale;
      float mx = fmaxf(fmaxf(sv[0], sv[1]), fmaxf(sv[2], sv[3]));
#pragma unroll
      for (int off = 1; off <= 8; off <<= 1) mx = fmaxf(mx, __shfl_xor(mx, off));
      float mn = fmaxf(mrow[r], mx);
      float rs = 0.f;
      int prow = 16 * w + 4 * hh + r;
#pragma unroll
      for (int f = 0; f < 4; ++f) {
        float p = __expf(sv[f] - mn);
        rs += p;
        plds[prow * 72 + 16 * f + l15] = f2h(p);
      }
#pragma unroll
      for (int off = 1; off <= 8; off <<= 1) rs += __shfl_xor(rs, off);
      float fs = __expf(mrow[r] - mn);
      lrow[r] = lrow[r] * fs + rs;
      mrow[r] = mn;
      if (l15 == 0) flds[prow] = fs;
    }
    asm volatile("s_waitcnt lgkmcnt(0)" ::: "memory");
    __builtin_amdgcn_s_barrier();
    // ---- O rescale + PV single-pass (chan-split: wave w owns chans 128w..+127) ----
#pragma unroll
    for (int rg = 0; rg < 4; ++rg) {
      float fr[4];
#pragma unroll
      for (int r = 0; r < 4; ++r) fr[r] = flds[16 * rg + 4 * hh + r];
#pragma unroll
      for (int cf = 0; cf < 8; ++cf)
#pragma unroll
        for (int r = 0; r < 4; ++r) Oacc[rg][cf][r] *= fr[r];
    }
#pragma unroll
    for (int kc = 0; kc < 2; ++kc) {
      f16x8 ap[4];
#pragma unroll
      for (int rg = 0; rg < 4; ++rg)
        ap[rg] = *(const f16x8*)&plds[(16 * rg + l15) * 72 + 32 * kc + 8 * hh];
#pragma unroll
      for (int cf = 0; cf < 8; ++cf) {
        int chan = 128 * w + 16 * cf + l15;
        f16x8 bv = *(const f16x8*)(vb + (size_t)chan * NPIX + ktof + 32 * kc + 8 * hh);
#pragma unroll
        for (int rg = 0; rg < 4; ++rg)
          Oacc[rg][cf] = __builtin_amdgcn_mfma_f32_16x16x32_f16(ap[rg], bv, Oacc[rg][cf], 0, 0, 0);
      }
    }
  }
  // ---- epilogue: opart[pair][chan][row] fp16, 4-row packed stores ----
  unsigned short* ob = opart + (size_t)pair * CDIM * NPIX;
#pragma unroll
  for (int rg = 0; rg < 4; ++rg)
#pragma unroll
    for (int cf = 0; cf < 8; ++cf) {
      int chan = 128 * w + 16 * cf + l15;
      ushort4v pk;
#pragma unroll
      for (int r = 0; r < 4; ++r) pk[r] = f2h(Oacc[rg][cf][r]);
      *(ushort4v*)(ob + (size_t)chan * NPIX + qBase + 16 * rg + 4 * hh) = pk;
    }
  if (l15 == 0) {
    size_t mlb = (size_t)pair * NPIX;
#pragma unroll
    for (int r = 0; r < 4; ++r) {
      int row = 16 * w + 4 * hh + r;
      mlbuf[(mlb + qBase + row) * 2 + 0] = mrow[r];
      mlbuf[(mlb + qBase + row) * 2 + 1] = lrow[r];
    }
  }
}

// ---------------- wn: per-row merge weights ----------------
__global__ __launch_bounds__(256)
void wn_kernel(const float* __restrict__ mlbuf, float* __restrict__ wn) {
  int idx = blockIdx.x * 256 + threadIdx.x;  // b*NPIX + i
  int b = idx >> 12;
  int i = idx & (NPIX - 1);
  float m[KS], l[KS], M = -1e30f;
#pragma unroll
  for (int ks = 0; ks < KS; ++ks) {
    size_t p = ((size_t)(b * KS + ks) * NPIX + i) * 2;
    m[ks] = mlbuf[p];
    l[ks] = mlbuf[p + 1];
    M = fmaxf(M, m[ks]);
  }
  float den = 0.f;
#pragma unroll
  for (int ks = 0; ks < KS; ++ks) den += __expf(m[ks] - M) * l[ks];
  float rden = 1.f / den;
#pragma unroll
  for (int ks = 0; ks < KS; ++ks)
    wn[(size_t)(b * KS + ks) * NPIX + i] = __expf(m[ks] - M) * rden;
}

// ---------------- combine: ao[b][c][i] = sum_ks wn*opart (coalesced elementwise) ----------------
__global__ __launch_bounds__(256)
void combine_kernel(const unsigned short* __restrict__ opart, const float* __restrict__ wn,
                    float* __restrict__ ao) {
  size_t idx = (size_t)blockIdx.x * 256 + threadIdx.x;  // over B*CDIM*NPIX/8
  size_t e = idx * 8;
  int i = (int)(e & (NPIX - 1));
  size_t bc = e >> 12;  // b*CDIM + c
  int b = (int)(bc >> 9);
  int c = (int)(bc & 511);
  float acc[8] = {};
#pragma unroll
  for (int ks = 0; ks < KS; ++ks) {
    const unsigned short* op = opart + ((size_t)(b * KS + ks) * CDIM + c) * NPIX + i;
    ushort8v ov = *(const ushort8v*)op;
    const float* wp = wn + (size_t)(b * KS + ks) * NPIX + i;
    float4 w0 = *(const float4*)wp;
    float4 w1 = *(const float4*)(wp + 4);
    acc[0] += w0.x * h2f(ov[0]);
    acc[1] += w0.y * h2f(ov[1]);
    acc[2] += w0.z * h2f(ov[2]);
    acc[3] += w0.w * h2f(ov[3]);
    acc[4] += w1.x * h2f(ov[4]);
    acc[5] += w1.y * h2f(ov[5]);
    acc[6] += w1.z * h2f(ov[6]);
    acc[7] += w1.w * h2f(ov[7]);
  }
  float* dst = ao + bc * NPIX + i;
  float4 o0 = {acc[0], acc[1], acc[2], acc[3]};
  float4 o1 = {acc[4], acc[5], acc[6], acc[7]};
  *(float4*)dst = o0;
  *(float4*)(dst + 4) = o1;
}

extern "C" void kernel_launch(void* const* d_in, const int* in_sizes, int n_in,
                              void* d_out, int out_size, void* d_ws, size_t ws_size,
                              hipStream_t stream) {
  const float* x     = (const float*)d_in[0];
  const float* gamma = (const float*)d_in[1];
  const float* beta  = (const float*)d_in[2];
  const float* wq    = (const float*)d_in[3];
  const float* bq    = (const float*)d_in[4];
  const float* wk    = (const float*)d_in[5];
  const float* bk    = (const float*)d_in[6];
  const float* wv    = (const float*)d_in[7];
  const float* bv    = (const float*)d_in[8];
  const float* wp    = (const float*)d_in[9];
  const float* bp    = (const float*)d_in[10];
  float* out = (float*)d_out;

  const size_t per = (size_t)BATCH * CDIM * NPIX;  // 4,194,304
  char* ws = (char*)d_ws;
  // opart: B*KS partials, fp16 [pair][chan][row] = 16 * 4MB = 64MB. h (fp32 16.8MB) aliases it.
  unsigned short* opart = (unsigned short*)ws;
  float* h = (float*)ws;
  unsigned short* qt_hi = (unsigned short*)(ws + (size_t)BATCH * KS * CDIM * NPIX * 2);
  unsigned short* qt_lo = qt_hi + per;
  unsigned short* kt_hi = qt_lo + per;
  unsigned short* kt_lo = kt_hi + per;
  unsigned short* vbuf  = kt_lo + per;
  float* mlbuf = (float*)(vbuf + per);                       // 16*4096*2 fp32 = 0.5MB
  float* wn    = mlbuf + (size_t)BATCH * KS * NPIX * 2;      // 16*4096 fp32 = 0.25MB
  float* ao    = (float*)qt_hi;                              // q hi+lo dead after attn

  gn_kernel<<<dim3(BATCH * NGROUP), dim3(1024), 0, stream>>>(x, gamma, beta, h);
  dim3 cgrid(NPIX / 64, CDIM / 64, BATCH);
  conv1x1_kernel<1><<<cgrid, 256, 0, stream>>>(wq, bq, h, nullptr, nullptr, qt_hi, qt_lo);
  conv1x1_kernel<1><<<cgrid, 256, 0, stream>>>(wk, bk, h, nullptr, nullptr, kt_hi, kt_lo);
  conv1x1_kernel<2><<<cgrid, 256, 0, stream>>>(wv, bv, h, nullptr, nullptr, vbuf, nullptr);
  attn_kernel<<<dim3((NPIX / QT) * BATCH * KS), 256, 0, stream>>>(qt_hi, qt_lo, kt_hi, kt_lo,
                                                                  vbuf, opart, mlbuf);
  wn_kernel<<<dim3(BATCH * NPIX / 256), 256, 0, stream>>>(mlbuf, wn);
  combine_kernel<<<dim3((unsigned)(per / 8 / 256)), 256, 0, stream>>>(opart, wn, ao);
  conv1x1_kernel<0><<<cgrid, 256, 0, stream>>>(wp, bp, ao, x, out, nullptr, nullptr);
}

// Round 11
// 676.497 us; speedup vs baseline: 1.1786x; 1.1786x over previous
//
#include <hip/hip_runtime.h>
#include <hip/hip_bf16.h>
#include <math.h>

#define CDIM 512
#define NPIX 4096
#define BATCH 2
#define NGROUP 32
#define CPG 16
#define EPSV 1e-6f

#define QT 64
#define KT 64
#define KS 8
#define KEYS_PER (NPIX / KS)   // 512
#define NKT (KEYS_PER / KT)    // 8
#define NWIN (NKT * 4)         // 32 chunk-windows (64 keys x 128 chans each)

typedef __attribute__((ext_vector_type(4))) float f32x4;
typedef _Float16 f16x8 __attribute__((ext_vector_type(8)));
typedef __attribute__((ext_vector_type(8))) unsigned short ushort8v;
typedef __attribute__((ext_vector_type(4))) unsigned short ushort4v;

__device__ inline unsigned short f2h(float x) {
  _Float16 h = (_Float16)x;
  return __builtin_bit_cast(unsigned short, h);
}
__device__ inline float h2f(unsigned short u) {
  return (float)__builtin_bit_cast(_Float16, u);
}

__device__ inline void gload_lds16(const void* g, void* l) {
  __builtin_amdgcn_global_load_lds((const __attribute__((address_space(1))) void*)g,
                                   (__attribute__((address_space(3))) void*)l, 16, 0, 0);
}

// ---------------- GroupNorm ----------------
__global__ __launch_bounds__(1024)
void gn_kernel(const float* __restrict__ x, const float* __restrict__ gamma,
               const float* __restrict__ beta, float* __restrict__ h) {
  const int NE = CPG * NPIX;
  int b = blockIdx.x >> 5;
  int g = blockIdx.x & 31;
  size_t base = ((size_t)b * CDIM + (size_t)g * CPG) * NPIX;
  const float4* xv = (const float4*)(x + base);
  float4* hv = (float4*)(h + base);
  int t = threadIdx.x;
  float s = 0.f, ss = 0.f;
  for (int i = t; i < NE / 4; i += 1024) {
    float4 v = xv[i];
    s += (v.x + v.y) + (v.z + v.w);
    ss += v.x * v.x + v.y * v.y + v.z * v.z + v.w * v.w;
  }
#pragma unroll
  for (int off = 32; off >= 1; off >>= 1) {
    s += __shfl_down(s, off);
    ss += __shfl_down(ss, off);
  }
  __shared__ float redS[16], redQ[16];
  int wid = t >> 6;
  if ((t & 63) == 0) { redS[wid] = s; redQ[wid] = ss; }
  __syncthreads();
  __shared__ float s_mu, s_rs;
  if (t == 0) {
    float S = 0.f, Q = 0.f;
    for (int w = 0; w < 16; ++w) { S += redS[w]; Q += redQ[w]; }
    float mu = S / NE;
    float var = Q / NE - mu * mu;
    s_mu = mu;
    s_rs = rsqrtf(var + EPSV);
  }
  __syncthreads();
  float mu = s_mu, rs = s_rs;
  for (int i = t; i < NE / 4; i += 1024) {
    int c = g * CPG + (i >> 10);
    float ga = gamma[c] * rs;
    float be = beta[c] - mu * ga;
    float4 v = xv[i];
    v.x = v.x * ga + be;
    v.y = v.y * ga + be;
    v.z = v.z * ga + be;
    v.w = v.w * ga + be;
    hv[i] = v;
  }
}

// ---------------- conv1x1 GEMM ----------------
// MODE 0: fp32 out + residual (proj). MODE 1: fp16 TRANSPOSED out [b][n][c] (q,k).
// MODE 2: fp16 out [b][c][n] (v).
#define BKc 16
#define WPAD 68

template <int MODE>
__global__ __launch_bounds__(256)
void conv1x1_kernel(const float* __restrict__ W, const float* __restrict__ bias,
                    const float* __restrict__ src, const float* __restrict__ resid,
                    float* __restrict__ dst, unsigned short* __restrict__ dsth) {
  __shared__ __align__(16) float w_lds[BKc][WPAD];
  __shared__ __align__(16) float h_lds[BKc][64];
  __shared__ __align__(16) unsigned short t_lds[64][72];
  int t = threadIdx.x;
  int nBase = blockIdx.x * 64;
  int oBase = blockIdx.y * 64;
  int b = blockIdx.z;
  const float* srcb = src + (size_t)b * CDIM * NPIX;
  float acc[4][4] = {};
  int o0 = 4 * (t >> 4);
  int j0 = 4 * (t & 15);
  for (int c0 = 0; c0 < CDIM; c0 += BKc) {
    __syncthreads();
#pragma unroll
    for (int kk = 0; kk < 4; ++kk) {
      int idx = t + 256 * kk;
      int o_l = idx >> 4, c_l = idx & 15;
      w_lds[c_l][o_l] = W[(size_t)(oBase + o_l) * CDIM + c0 + c_l];
    }
#pragma unroll
    for (int kk = 0; kk < 4; ++kk) {
      int idx = t + 256 * kk;
      int c_l = idx >> 6, j = idx & 63;
      h_lds[c_l][j] = srcb[(size_t)(c0 + c_l) * NPIX + nBase + j];
    }
    __syncthreads();
#pragma unroll
    for (int kk = 0; kk < BKc; ++kk) {
      float4 a = *(const float4*)&w_lds[kk][o0];
      float4 bv = *(const float4*)&h_lds[kk][j0];
      float av[4] = {a.x, a.y, a.z, a.w};
      float bb[4] = {bv.x, bv.y, bv.z, bv.w};
#pragma unroll
      for (int r = 0; r < 4; ++r)
#pragma unroll
        for (int s2 = 0; s2 < 4; ++s2) acc[r][s2] += av[r] * bb[s2];
    }
  }
  if (MODE == 0) {
#pragma unroll
    for (int r = 0; r < 4; ++r) {
      int o = oBase + o0 + r;
      float bi = bias[o];
      size_t off = ((size_t)b * CDIM + o) * NPIX + nBase + j0;
      float4 out;
      out.x = acc[r][0] + bi;
      out.y = acc[r][1] + bi;
      out.z = acc[r][2] + bi;
      out.w = acc[r][3] + bi;
      float4 rv = *(const float4*)(resid + off);
      out.x += rv.x; out.y += rv.y; out.z += rv.z; out.w += rv.w;
      *(float4*)(dst + off) = out;
    }
  } else if (MODE == 2) {
#pragma unroll
    for (int r = 0; r < 4; ++r) {
      int o = oBase + o0 + r;
      float bi = bias[o];
      size_t off = ((size_t)b * CDIM + o) * NPIX + nBase + j0;
      ushort4v hv;
#pragma unroll
      for (int s2 = 0; s2 < 4; ++s2) hv[s2] = f2h(acc[r][s2] + bi);
      *(ushort4v*)(dsth + off) = hv;
    }
  } else {
    // MODE 1: single fp16, transpose via LDS
    float biv[4];
#pragma unroll
    for (int r = 0; r < 4; ++r) biv[r] = bias[oBase + o0 + r];
    __syncthreads();
#pragma unroll
    for (int r = 0; r < 4; ++r)
#pragma unroll
      for (int s2 = 0; s2 < 4; ++s2)
        t_lds[j0 + s2][o0 + r] = f2h(acc[r][s2] + biv[r]);
    __syncthreads();
    int row = t >> 2, seg = t & 3;
    size_t goff = ((size_t)b * NPIX + nBase + row) * CDIM + oBase + seg * 16;
#pragma unroll
    for (int e = 0; e < 2; ++e)
      *(ushort8v*)(dsth + goff + 8 * e) = *(ushort8v*)&t_lds[row][seg * 16 + 8 * e];
  }
}

// ---------------- MFMA flash attention (single fp16) ----------------
// 256 thr (4 waves). QT=64 rows, KT=64 keys/tile, KS=8 key-splits.
// Q cached in REGISTERS (16 f16x8 per thread) -> Q fetched once (R10's 1GB Q
// re-read was the FETCH dominator). K single fp16, staged in LDS as 32 windows
// of 64keys x 128chans: triple-buffered, one barrier/window, depth-2 prefetch,
// vmcnt(4) steady-state. S single-pass fp16 (err ~4e-3 on N(0,1) scores, far
// under threshold). PV unchanged. Epilogue unchanged (next round's variable).
__global__ __launch_bounds__(256, 2)
void attn_kernel(const unsigned short* __restrict__ qt, const unsigned short* __restrict__ kt_,
                 const unsigned short* __restrict__ vbuf,
                 unsigned short* __restrict__ opart, float* __restrict__ mlbuf) {
  __shared__ __align__(16) unsigned short ktile[3][64 * 128];  // 3 x 16KB [key][slot], slot=cb^(key&15)
  __shared__ __align__(16) unsigned short plds[64 * 72];       // P fp16 [row][key+pad]
  __shared__ float flds[64];

  int t = threadIdx.x;
  int lane = t & 63;
  int l15 = lane & 15;
  int hh = lane >> 4;
  int w = t >> 6;
  int bid = blockIdx.x;
  int pair = bid & 15;           // == b*KS + ks (matches wn/combine ordering)
  int b = pair >> 3;
  int ks = pair & 7;
  int qtile = bid >> 4;
  int qBase = qtile * QT;

  const unsigned short* kb = kt_ + ((size_t)b * NPIX + ks * KEYS_PER) * CDIM;
  const unsigned short* vb = vbuf + (size_t)b * CDIM * NPIX + ks * KEYS_PER;

  // Q fragments hoisted to registers: row 16w+l15, k-slice 32cc+8hh
  const unsigned short* qrow =
      qt + ((size_t)b * NPIX + qBase + 16 * w + l15) * CDIM + 8 * hh;
  f16x8 qf[16];
#pragma unroll
  for (int cc = 0; cc < 16; ++cc) qf[cc] = *(const f16x8*)(qrow + 32 * cc);

  f32x4 Oacc[4][8];
#pragma unroll
  for (int rg = 0; rg < 4; ++rg)
#pragma unroll
    for (int cf = 0; cf < 8; ++cf) Oacc[rg][cf] = (f32x4){0.f, 0.f, 0.f, 0.f};
  float mrow[4], lrow[4];
#pragma unroll
  for (int r = 0; r < 4; ++r) { mrow[r] = -1e30f; lrow[r] = 0.f; }

  const float scale = 0.044194173824159216f;

  // issue window g: 64 keys x 128 chans, 16 gload instrs (4/thread)
  auto issue = [&](int g) {
    int ch2 = g & 3;
    int ktof = (g >> 2) * KT;
    int d = g % 3;
#pragma unroll
    for (int j = 0; j < 4; ++j) {
      int idx = w * 4 + j;                 // 0..15
      int key = idx * 4 + (lane >> 4);     // 0..63
      int s = lane & 15;
      int cb = s ^ (key & 15);             // pre-swizzled source chan-block
      gload_lds16(kb + (size_t)(ktof + key) * CDIM + ch2 * 128 + cb * 8,
                  &ktile[d][idx * 512]);   // idx*512 halves = idx*1KB; HW adds lane*16B
    }
  };

  issue(0);
  issue(1);

  for (int kt = 0; kt < NKT; ++kt) {
    f32x4 Sacc[4];
#pragma unroll
    for (int f = 0; f < 4; ++f) Sacc[f] = (f32x4){0.f, 0.f, 0.f, 0.f};
    for (int ch2 = 0; ch2 < 4; ++ch2) {
      int g = kt * 4 + ch2;
      if (g + 1 < NWIN) {
        asm volatile("s_waitcnt vmcnt(4)" ::: "memory");  // window g landed
      } else {
        asm volatile("s_waitcnt vmcnt(0)" ::: "memory");
      }
      __builtin_amdgcn_s_barrier();
      if (g + 2 < NWIN) issue(g + 2);  // writes buf (g+2)%3==(g-1)%3: readers done pre-barrier
      int d = g % 3;
#pragma unroll
      for (int sc = 0; sc < 4; ++sc) {
        int cc = ch2 * 4 + sc;
        int cbl = sc * 4 + hh;
#pragma unroll
        for (int f = 0; f < 4; ++f) {
          int slot = cbl ^ l15;  // key&15 == l15
          f16x8 bh = *(const f16x8*)&ktile[d][(16 * f + l15) * 128 + slot * 8];
          Sacc[f] = __builtin_amdgcn_mfma_f32_16x16x32_f16(qf[cc], bh, Sacc[f], 0, 0, 0);
        }
      }
    }
    int ktof = kt * KT;
    // ---- online softmax (rows 16w..16w+15; D-frag col=l15=key, row=4hh+r) ----
#pragma unroll
    for (int r = 0; r < 4; ++r) {
      float sv[4];
#pragma unroll
      for (int f = 0; f < 4; ++f) sv[f] = Sacc[f][r] * scale;
      float mx = fmaxf(fmaxf(sv[0], sv[1]), fmaxf(sv[2], sv[3]));
#pragma unroll
      for (int off = 1; off <= 8; off <<= 1) mx = fmaxf(mx, __shfl_xor(mx, off));
      float mn = fmaxf(mrow[r], mx);
      float rs = 0.f;
      int prow = 16 * w + 4 * hh + r;
#pragma unroll
      for (int f = 0; f < 4; ++f) {
        float p = __expf(sv[f] - mn);
        rs += p;
        plds[prow * 72 + 16 * f + l15] = f2h(p);
      }
#pragma unroll
      for (int off = 1; off <= 8; off <<= 1) rs += __shfl_xor(rs, off);
      float fs = __expf(mrow[r] - mn);
      lrow[r] = lrow[r] * fs + rs;
      mrow[r] = mn;
      if (l15 == 0) flds[prow] = fs;
    }
    asm volatile("s_waitcnt lgkmcnt(0)" ::: "memory");
    __builtin_amdgcn_s_barrier();
    // ---- O rescale + PV (chan-split: wave w owns chans 128w..+127) ----
#pragma unroll
    for (int rg = 0; rg < 4; ++rg) {
      float fr[4];
#pragma unroll
      for (int r = 0; r < 4; ++r) fr[r] = flds[16 * rg + 4 * hh + r];
#pragma unroll
      for (int cf = 0; cf < 8; ++cf)
#pragma unroll
        for (int r = 0; r < 4; ++r) Oacc[rg][cf][r] *= fr[r];
    }
#pragma unroll
    for (int kc = 0; kc < 2; ++kc) {
      f16x8 ap[4];
#pragma unroll
      for (int rg = 0; rg < 4; ++rg)
        ap[rg] = *(const f16x8*)&plds[(16 * rg + l15) * 72 + 32 * kc + 8 * hh];
#pragma unroll
      for (int cf = 0; cf < 8; ++cf) {
        int chan = 128 * w + 16 * cf + l15;
        f16x8 bv = *(const f16x8*)(vb + (size_t)chan * NPIX + ktof + 32 * kc + 8 * hh);
#pragma unroll
        for (int rg = 0; rg < 4; ++rg)
          Oacc[rg][cf] = __builtin_amdgcn_mfma_f32_16x16x32_f16(ap[rg], bv, Oacc[rg][cf], 0, 0, 0);
      }
    }
  }
  // ---- epilogue: opart[pair][chan][row] fp16, 4-row packed stores ----
  unsigned short* ob = opart + (size_t)pair * CDIM * NPIX;
#pragma unroll
  for (int rg = 0; rg < 4; ++rg)
#pragma unroll
    for (int cf = 0; cf < 8; ++cf) {
      int chan = 128 * w + 16 * cf + l15;
      ushort4v pk;
#pragma unroll
      for (int r = 0; r < 4; ++r) pk[r] = f2h(Oacc[rg][cf][r]);
      *(ushort4v*)(ob + (size_t)chan * NPIX + qBase + 16 * rg + 4 * hh) = pk;
    }
  if (l15 == 0) {
    size_t mlb = (size_t)pair * NPIX;
#pragma unroll
    for (int r = 0; r < 4; ++r) {
      int row = 16 * w + 4 * hh + r;
      mlbuf[(mlb + qBase + row) * 2 + 0] = mrow[r];
      mlbuf[(mlb + qBase + row) * 2 + 1] = lrow[r];
    }
  }
}

// ---------------- wn: per-row merge weights ----------------
__global__ __launch_bounds__(256)
void wn_kernel(const float* __restrict__ mlbuf, float* __restrict__ wn) {
  int idx = blockIdx.x * 256 + threadIdx.x;  // b*NPIX + i
  int b = idx >> 12;
  int i = idx & (NPIX - 1);
  float m[KS], l[KS], M = -1e30f;
#pragma unroll
  for (int ks = 0; ks < KS; ++ks) {
    size_t p = ((size_t)(b * KS + ks) * NPIX + i) * 2;
    m[ks] = mlbuf[p];
    l[ks] = mlbuf[p + 1];
    M = fmaxf(M, m[ks]);
  }
  float den = 0.f;
#pragma unroll
  for (int ks = 0; ks < KS; ++ks) den += __expf(m[ks] - M) * l[ks];
  float rden = 1.f / den;
#pragma unroll
  for (int ks = 0; ks < KS; ++ks)
    wn[(size_t)(b * KS + ks) * NPIX + i] = __expf(m[ks] - M) * rden;
}

// ---------------- combine: ao[b][c][i] = sum_ks wn*opart ----------------
__global__ __launch_bounds__(256)
void combine_kernel(const unsigned short* __restrict__ opart, const float* __restrict__ wn,
                    float* __restrict__ ao) {
  size_t idx = (size_t)blockIdx.x * 256 + threadIdx.x;  // over B*CDIM*NPIX/8
  size_t e = idx * 8;
  int i = (int)(e & (NPIX - 1));
  size_t bc = e >> 12;  // b*CDIM + c
  int b = (int)(bc >> 9);
  int c = (int)(bc & 511);
  float acc[8] = {};
#pragma unroll
  for (int ks = 0; ks < KS; ++ks) {
    const unsigned short* op = opart + ((size_t)(b * KS + ks) * CDIM + c) * NPIX + i;
    ushort8v ov = *(const ushort8v*)op;
    const float* wp = wn + (size_t)(b * KS + ks) * NPIX + i;
    float4 w0 = *(const float4*)wp;
    float4 w1 = *(const float4*)(wp + 4);
    acc[0] += w0.x * h2f(ov[0]);
    acc[1] += w0.y * h2f(ov[1]);
    acc[2] += w0.z * h2f(ov[2]);
    acc[3] += w0.w * h2f(ov[3]);
    acc[4] += w1.x * h2f(ov[4]);
    acc[5] += w1.y * h2f(ov[5]);
    acc[6] += w1.z * h2f(ov[6]);
    acc[7] += w1.w * h2f(ov[7]);
  }
  float* dst = ao + bc * NPIX + i;
  float4 o0 = {acc[0], acc[1], acc[2], acc[3]};
  float4 o1 = {acc[4], acc[5], acc[6], acc[7]};
  *(float4*)dst = o0;
  *(float4*)(dst + 4) = o1;
}

extern "C" void kernel_launch(void* const* d_in, const int* in_sizes, int n_in,
                              void* d_out, int out_size, void* d_ws, size_t ws_size,
                              hipStream_t stream) {
  const float* x     = (const float*)d_in[0];
  const float* gamma = (const float*)d_in[1];
  const float* beta  = (const float*)d_in[2];
  const float* wq    = (const float*)d_in[3];
  const float* bq    = (const float*)d_in[4];
  const float* wk    = (const float*)d_in[5];
  const float* bk    = (const float*)d_in[6];
  const float* wv    = (const float*)d_in[7];
  const float* bv    = (const float*)d_in[8];
  const float* wp    = (const float*)d_in[9];
  const float* bp    = (const float*)d_in[10];
  float* out = (float*)d_out;

  const size_t per = (size_t)BATCH * CDIM * NPIX;  // 4,194,304
  char* ws = (char*)d_ws;
  // opart: 16 partials fp16 [pair][chan][row] = 64MB. h (fp32 16.8MB) aliases it.
  unsigned short* opart = (unsigned short*)ws;
  float* h = (float*)ws;
  unsigned short* qbuf = (unsigned short*)(ws + (size_t)BATCH * KS * CDIM * NPIX * 2);
  unsigned short* kbuf = qbuf + per;
  unsigned short* vbuf = kbuf + per;
  float* mlbuf = (float*)(vbuf + per);                   // 16*4096*2 fp32 = 0.5MB
  float* wn    = mlbuf + (size_t)BATCH * KS * NPIX * 2;  // 16*4096 fp32 = 0.25MB
  float* ao    = (float*)qbuf;                           // q+k dead after attn (16.8MB)

  gn_kernel<<<dim3(BATCH * NGROUP), dim3(1024), 0, stream>>>(x, gamma, beta, h);
  dim3 cgrid(NPIX / 64, CDIM / 64, BATCH);
  conv1x1_kernel<1><<<cgrid, 256, 0, stream>>>(wq, bq, h, nullptr, nullptr, qbuf);
  conv1x1_kernel<1><<<cgrid, 256, 0, stream>>>(wk, bk, h, nullptr, nullptr, kbuf);
  conv1x1_kernel<2><<<cgrid, 256, 0, stream>>>(wv, bv, h, nullptr, nullptr, vbuf);
  attn_kernel<<<dim3((NPIX / QT) * BATCH * KS), 256, 0, stream>>>(qbuf, kbuf, vbuf, opart, mlbuf);
  wn_kernel<<<dim3(BATCH * NPIX / 256), 256, 0, stream>>>(mlbuf, wn);
  combine_kernel<<<dim3((unsigned)(per / 8 / 256)), 256, 0, stream>>>(opart, wn, ao);
  conv1x1_kernel<0><<<cgrid, 256, 0, stream>>>(wp, bp, ao, x, out, nullptr);
}

// Round 12
// 665.405 us; speedup vs baseline: 1.1982x; 1.0167x over previous
//
#include <hip/hip_runtime.h>
#include <hip/hip_bf16.h>
#include <math.h>

#define CDIM 512
#define NPIX 4096
#define BATCH 2
#define NGROUP 32
#define CPG 16
#define EPSV 1e-6f

#define QT 64
#define KT 64
#define KS 4
#define KEYS_PER (NPIX / KS)   // 1024
#define NKT (KEYS_PER / KT)    // 16
#define NWIN (NKT * 4)         // 64 chunk-windows (64 keys x 128 chans each)

typedef __attribute__((ext_vector_type(4))) float f32x4;
typedef _Float16 f16x8 __attribute__((ext_vector_type(8)));
typedef __attribute__((ext_vector_type(8))) unsigned short ushort8v;
typedef __attribute__((ext_vector_type(4))) unsigned short ushort4v;

__device__ inline unsigned short f2h(float x) {
  _Float16 h = (_Float16)x;
  return __builtin_bit_cast(unsigned short, h);
}
__device__ inline float h2f(unsigned short u) {
  return (float)__builtin_bit_cast(_Float16, u);
}

__device__ inline void gload_lds16(const void* g, void* l) {
  __builtin_amdgcn_global_load_lds((const __attribute__((address_space(1))) void*)g,
                                   (__attribute__((address_space(3))) void*)l, 16, 0, 0);
}

// ---------------- GroupNorm ----------------
__global__ __launch_bounds__(1024)
void gn_kernel(const float* __restrict__ x, const float* __restrict__ gamma,
               const float* __restrict__ beta, float* __restrict__ h) {
  const int NE = CPG * NPIX;
  int b = blockIdx.x >> 5;
  int g = blockIdx.x & 31;
  size_t base = ((size_t)b * CDIM + (size_t)g * CPG) * NPIX;
  const float4* xv = (const float4*)(x + base);
  float4* hv = (float4*)(h + base);
  int t = threadIdx.x;
  float s = 0.f, ss = 0.f;
  for (int i = t; i < NE / 4; i += 1024) {
    float4 v = xv[i];
    s += (v.x + v.y) + (v.z + v.w);
    ss += v.x * v.x + v.y * v.y + v.z * v.z + v.w * v.w;
  }
#pragma unroll
  for (int off = 32; off >= 1; off >>= 1) {
    s += __shfl_down(s, off);
    ss += __shfl_down(ss, off);
  }
  __shared__ float redS[16], redQ[16];
  int wid = t >> 6;
  if ((t & 63) == 0) { redS[wid] = s; redQ[wid] = ss; }
  __syncthreads();
  __shared__ float s_mu, s_rs;
  if (t == 0) {
    float S = 0.f, Q = 0.f;
    for (int w = 0; w < 16; ++w) { S += redS[w]; Q += redQ[w]; }
    float mu = S / NE;
    float var = Q / NE - mu * mu;
    s_mu = mu;
    s_rs = rsqrtf(var + EPSV);
  }
  __syncthreads();
  float mu = s_mu, rs = s_rs;
  for (int i = t; i < NE / 4; i += 1024) {
    int c = g * CPG + (i >> 10);
    float ga = gamma[c] * rs;
    float be = beta[c] - mu * ga;
    float4 v = xv[i];
    v.x = v.x * ga + be;
    v.y = v.y * ga + be;
    v.z = v.z * ga + be;
    v.w = v.w * ga + be;
    hv[i] = v;
  }
}

// ---------------- conv1x1 GEMM ----------------
// MODE 0: fp32 out + residual (proj). MODE 1: fp16 TRANSPOSED out [b][n][c] (q,k).
// MODE 2: fp16 out [b][c][n] (v).
#define BKc 16
#define WPAD 68

template <int MODE>
__global__ __launch_bounds__(256)
void conv1x1_kernel(const float* __restrict__ W, const float* __restrict__ bias,
                    const float* __restrict__ src, const float* __restrict__ resid,
                    float* __restrict__ dst, unsigned short* __restrict__ dsth) {
  __shared__ __align__(16) float w_lds[BKc][WPAD];
  __shared__ __align__(16) float h_lds[BKc][64];
  __shared__ __align__(16) unsigned short t_lds[64][72];
  int t = threadIdx.x;
  int nBase = blockIdx.x * 64;
  int oBase = blockIdx.y * 64;
  int b = blockIdx.z;
  const float* srcb = src + (size_t)b * CDIM * NPIX;
  float acc[4][4] = {};
  int o0 = 4 * (t >> 4);
  int j0 = 4 * (t & 15);
  for (int c0 = 0; c0 < CDIM; c0 += BKc) {
    __syncthreads();
#pragma unroll
    for (int kk = 0; kk < 4; ++kk) {
      int idx = t + 256 * kk;
      int o_l = idx >> 4, c_l = idx & 15;
      w_lds[c_l][o_l] = W[(size_t)(oBase + o_l) * CDIM + c0 + c_l];
    }
#pragma unroll
    for (int kk = 0; kk < 4; ++kk) {
      int idx = t + 256 * kk;
      int c_l = idx >> 6, j = idx & 63;
      h_lds[c_l][j] = srcb[(size_t)(c0 + c_l) * NPIX + nBase + j];
    }
    __syncthreads();
#pragma unroll
    for (int kk = 0; kk < BKc; ++kk) {
      float4 a = *(const float4*)&w_lds[kk][o0];
      float4 bv = *(const float4*)&h_lds[kk][j0];
      float av[4] = {a.x, a.y, a.z, a.w};
      float bb[4] = {bv.x, bv.y, bv.z, bv.w};
#pragma unroll
      for (int r = 0; r < 4; ++r)
#pragma unroll
        for (int s2 = 0; s2 < 4; ++s2) acc[r][s2] += av[r] * bb[s2];
    }
  }
  if (MODE == 0) {
#pragma unroll
    for (int r = 0; r < 4; ++r) {
      int o = oBase + o0 + r;
      float bi = bias[o];
      size_t off = ((size_t)b * CDIM + o) * NPIX + nBase + j0;
      float4 out;
      out.x = acc[r][0] + bi;
      out.y = acc[r][1] + bi;
      out.z = acc[r][2] + bi;
      out.w = acc[r][3] + bi;
      float4 rv = *(const float4*)(resid + off);
      out.x += rv.x; out.y += rv.y; out.z += rv.z; out.w += rv.w;
      *(float4*)(dst + off) = out;
    }
  } else if (MODE == 2) {
#pragma unroll
    for (int r = 0; r < 4; ++r) {
      int o = oBase + o0 + r;
      float bi = bias[o];
      size_t off = ((size_t)b * CDIM + o) * NPIX + nBase + j0;
      ushort4v hv;
#pragma unroll
      for (int s2 = 0; s2 < 4; ++s2) hv[s2] = f2h(acc[r][s2] + bi);
      *(ushort4v*)(dsth + off) = hv;
    }
  } else {
    // MODE 1: single fp16, transpose via LDS
    float biv[4];
#pragma unroll
    for (int r = 0; r < 4; ++r) biv[r] = bias[oBase + o0 + r];
    __syncthreads();
#pragma unroll
    for (int r = 0; r < 4; ++r)
#pragma unroll
      for (int s2 = 0; s2 < 4; ++s2)
        t_lds[j0 + s2][o0 + r] = f2h(acc[r][s2] + biv[r]);
    __syncthreads();
    int row = t >> 2, seg = t & 3;
    size_t goff = ((size_t)b * NPIX + nBase + row) * CDIM + oBase + seg * 16;
#pragma unroll
    for (int e = 0; e < 2; ++e)
      *(ushort8v*)(dsth + goff + 8 * e) = *(ushort8v*)&t_lds[row][seg * 16 + 8 * e];
  }
}

// ---------------- MFMA flash attention (single fp16, KS=4) ----------------
// 256 thr (4 waves). QT=64 rows, KT=64 keys/tile, KS=4 key-splits.
// Grid 512 = 2 blocks/CU; pair = bid&7 -> each XCD owns exactly ONE (b,ks)
// panel (K+V = 2MB, L2-resident; R11's KS=8 put 2 pairs/XCD and thrashed).
// Q cached in registers (fetched once). K staged in LDS: 64 windows of
// 64keys x 128chans, triple-buffered, one barrier/window, depth-2 prefetch,
// vmcnt(4) steady-state. S single-pass fp16; PV single-pass fp16.
__global__ __launch_bounds__(256, 2)
void attn_kernel(const unsigned short* __restrict__ qt, const unsigned short* __restrict__ kt_,
                 const unsigned short* __restrict__ vbuf,
                 unsigned short* __restrict__ opart, float* __restrict__ mlbuf) {
  __shared__ __align__(16) unsigned short ktile[3][64 * 128];  // 3 x 16KB [key][slot], slot=cb^(key&15)
  __shared__ __align__(16) unsigned short plds[64 * 72];       // P fp16 [row][key+pad]
  __shared__ float flds[64];

  int t = threadIdx.x;
  int lane = t & 63;
  int l15 = lane & 15;
  int hh = lane >> 4;
  int w = t >> 6;
  int bid = blockIdx.x;
  int pair = bid & 7;            // == b*KS + ks; pair&7 == XCD -> one panel per XCD
  int b = pair >> 2;
  int ks = pair & 3;
  int qtile = bid >> 3;
  int qBase = qtile * QT;

  const unsigned short* kb = kt_ + ((size_t)b * NPIX + ks * KEYS_PER) * CDIM;
  const unsigned short* vb = vbuf + (size_t)b * CDIM * NPIX + ks * KEYS_PER;

  // Q fragments hoisted to registers: row 16w+l15, k-slice 32cc+8hh
  const unsigned short* qrow =
      qt + ((size_t)b * NPIX + qBase + 16 * w + l15) * CDIM + 8 * hh;
  f16x8 qf[16];
#pragma unroll
  for (int cc = 0; cc < 16; ++cc) qf[cc] = *(const f16x8*)(qrow + 32 * cc);

  f32x4 Oacc[4][8];
#pragma unroll
  for (int rg = 0; rg < 4; ++rg)
#pragma unroll
    for (int cf = 0; cf < 8; ++cf) Oacc[rg][cf] = (f32x4){0.f, 0.f, 0.f, 0.f};
  float mrow[4], lrow[4];
#pragma unroll
  for (int r = 0; r < 4; ++r) { mrow[r] = -1e30f; lrow[r] = 0.f; }

  const float scale = 0.044194173824159216f;

  // issue window g: 64 keys x 128 chans, 16 gload instrs (4/thread)
  auto issue = [&](int g) {
    int ch2 = g & 3;
    int ktof = (g >> 2) * KT;
    int d = g % 3;
#pragma unroll
    for (int j = 0; j < 4; ++j) {
      int idx = w * 4 + j;                 // 0..15
      int key = idx * 4 + (lane >> 4);     // 0..63
      int s = lane & 15;
      int cb = s ^ (key & 15);             // pre-swizzled source chan-block
      gload_lds16(kb + (size_t)(ktof + key) * CDIM + ch2 * 128 + cb * 8,
                  &ktile[d][idx * 512]);   // idx*512 halves = idx*1KB; HW adds lane*16B
    }
  };

  issue(0);
  issue(1);

  for (int kt = 0; kt < NKT; ++kt) {
    f32x4 Sacc[4];
#pragma unroll
    for (int f = 0; f < 4; ++f) Sacc[f] = (f32x4){0.f, 0.f, 0.f, 0.f};
    for (int ch2 = 0; ch2 < 4; ++ch2) {
      int g = kt * 4 + ch2;
      if (g + 1 < NWIN) {
        asm volatile("s_waitcnt vmcnt(4)" ::: "memory");  // window g landed
      } else {
        asm volatile("s_waitcnt vmcnt(0)" ::: "memory");
      }
      __builtin_amdgcn_s_barrier();
      if (g + 2 < NWIN) issue(g + 2);  // writes buf (g+2)%3==(g-1)%3: readers done pre-barrier
      int d = g % 3;
#pragma unroll
      for (int sc = 0; sc < 4; ++sc) {
        int cc = ch2 * 4 + sc;
        int cbl = sc * 4 + hh;
#pragma unroll
        for (int f = 0; f < 4; ++f) {
          int slot = cbl ^ l15;  // key&15 == l15
          f16x8 bh = *(const f16x8*)&ktile[d][(16 * f + l15) * 128 + slot * 8];
          Sacc[f] = __builtin_amdgcn_mfma_f32_16x16x32_f16(qf[cc], bh, Sacc[f], 0, 0, 0);
        }
      }
    }
    int ktof = kt * KT;
    // ---- online softmax (rows 16w..16w+15; D-frag col=l15=key, row=4hh+r) ----
#pragma unroll
    for (int r = 0; r < 4; ++r) {
      float sv[4];
#pragma unroll
      for (int f = 0; f < 4; ++f) sv[f] = Sacc[f][r] * scale;
      float mx = fmaxf(fmaxf(sv[0], sv[1]), fmaxf(sv[2], sv[3]));
#pragma unroll
      for (int off = 1; off <= 8; off <<= 1) mx = fmaxf(mx, __shfl_xor(mx, off));
      float mn = fmaxf(mrow[r], mx);
      float rs = 0.f;
      int prow = 16 * w + 4 * hh + r;
#pragma unroll
      for (int f = 0; f < 4; ++f) {
        float p = __expf(sv[f] - mn);
        rs += p;
        plds[prow * 72 + 16 * f + l15] = f2h(p);
      }
#pragma unroll
      for (int off = 1; off <= 8; off <<= 1) rs += __shfl_xor(rs, off);
      float fs = __expf(mrow[r] - mn);
      lrow[r] = lrow[r] * fs + rs;
      mrow[r] = mn;
      if (l15 == 0) flds[prow] = fs;
    }
    asm volatile("s_waitcnt lgkmcnt(0)" ::: "memory");
    __builtin_amdgcn_s_barrier();
    // ---- O rescale + PV (chan-split: wave w owns chans 128w..+127) ----
#pragma unroll
    for (int rg = 0; rg < 4; ++rg) {
      float fr[4];
#pragma unroll
      for (int r = 0; r < 4; ++r) fr[r] = flds[16 * rg + 4 * hh + r];
#pragma unroll
      for (int cf = 0; cf < 8; ++cf)
#pragma unroll
        for (int r = 0; r < 4; ++r) Oacc[rg][cf][r] *= fr[r];
    }
#pragma unroll
    for (int kc = 0; kc < 2; ++kc) {
      f16x8 ap[4];
#pragma unroll
      for (int rg = 0; rg < 4; ++rg)
        ap[rg] = *(const f16x8*)&plds[(16 * rg + l15) * 72 + 32 * kc + 8 * hh];
#pragma unroll
      for (int cf = 0; cf < 8; ++cf) {
        int chan = 128 * w + 16 * cf + l15;
        f16x8 bv = *(const f16x8*)(vb + (size_t)chan * NPIX + ktof + 32 * kc + 8 * hh);
#pragma unroll
        for (int rg = 0; rg < 4; ++rg)
          Oacc[rg][cf] = __builtin_amdgcn_mfma_f32_16x16x32_f16(ap[rg], bv, Oacc[rg][cf], 0, 0, 0);
      }
    }
  }
  // ---- epilogue: opart[pair][chan][row] fp16, 4-row packed stores ----
  unsigned short* ob = opart + (size_t)pair * CDIM * NPIX;
#pragma unroll
  for (int rg = 0; rg < 4; ++rg)
#pragma unroll
    for (int cf = 0; cf < 8; ++cf) {
      int chan = 128 * w + 16 * cf + l15;
      ushort4v pk;
#pragma unroll
      for (int r = 0; r < 4; ++r) pk[r] = f2h(Oacc[rg][cf][r]);
      *(ushort4v*)(ob + (size_t)chan * NPIX + qBase + 16 * rg + 4 * hh) = pk;
    }
  if (l15 == 0) {
    size_t mlb = (size_t)pair * NPIX;
#pragma unroll
    for (int r = 0; r < 4; ++r) {
      int row = 16 * w + 4 * hh + r;
      mlbuf[(mlb + qBase + row) * 2 + 0] = mrow[r];
      mlbuf[(mlb + qBase + row) * 2 + 1] = lrow[r];
    }
  }
}

// ---------------- wn: per-row merge weights ----------------
__global__ __launch_bounds__(256)
void wn_kernel(const float* __restrict__ mlbuf, float* __restrict__ wn) {
  int idx = blockIdx.x * 256 + threadIdx.x;  // b*NPIX + i
  int b = idx >> 12;
  int i = idx & (NPIX - 1);
  float m[KS], l[KS], M = -1e30f;
#pragma unroll
  for (int ks = 0; ks < KS; ++ks) {
    size_t p = ((size_t)(b * KS + ks) * NPIX + i) * 2;
    m[ks] = mlbuf[p];
    l[ks] = mlbuf[p + 1];
    M = fmaxf(M, m[ks]);
  }
  float den = 0.f;
#pragma unroll
  for (int ks = 0; ks < KS; ++ks) den += __expf(m[ks] - M) * l[ks];
  float rden = 1.f / den;
#pragma unroll
  for (int ks = 0; ks < KS; ++ks)
    wn[(size_t)(b * KS + ks) * NPIX + i] = __expf(m[ks] - M) * rden;
}

// ---------------- combine: ao[b][c][i] = sum_ks wn*opart ----------------
__global__ __launch_bounds__(256)
void combine_kernel(const unsigned short* __restrict__ opart, const float* __restrict__ wn,
                    float* __restrict__ ao) {
  size_t idx = (size_t)blockIdx.x * 256 + threadIdx.x;  // over B*CDIM*NPIX/8
  size_t e = idx * 8;
  int i = (int)(e & (NPIX - 1));
  size_t bc = e >> 12;  // b*CDIM + c
  int b = (int)(bc >> 9);
  int c = (int)(bc & 511);
  float acc[8] = {};
#pragma unroll
  for (int ks = 0; ks < KS; ++ks) {
    const unsigned short* op = opart + ((size_t)(b * KS + ks) * CDIM + c) * NPIX + i;
    ushort8v ov = *(const ushort8v*)op;
    const float* wp = wn + (size_t)(b * KS + ks) * NPIX + i;
    float4 w0 = *(const float4*)wp;
    float4 w1 = *(const float4*)(wp + 4);
    acc[0] += w0.x * h2f(ov[0]);
    acc[1] += w0.y * h2f(ov[1]);
    acc[2] += w0.z * h2f(ov[2]);
    acc[3] += w0.w * h2f(ov[3]);
    acc[4] += w1.x * h2f(ov[4]);
    acc[5] += w1.y * h2f(ov[5]);
    acc[6] += w1.z * h2f(ov[6]);
    acc[7] += w1.w * h2f(ov[7]);
  }
  float* dst = ao + bc * NPIX + i;
  float4 o0 = {acc[0], acc[1], acc[2], acc[3]};
  float4 o1 = {acc[4], acc[5], acc[6], acc[7]};
  *(float4*)dst = o0;
  *(float4*)(dst + 4) = o1;
}

extern "C" void kernel_launch(void* const* d_in, const int* in_sizes, int n_in,
                              void* d_out, int out_size, void* d_ws, size_t ws_size,
                              hipStream_t stream) {
  const float* x     = (const float*)d_in[0];
  const float* gamma = (const float*)d_in[1];
  const float* beta  = (const float*)d_in[2];
  const float* wq    = (const float*)d_in[3];
  const float* bq    = (const float*)d_in[4];
  const float* wk    = (const float*)d_in[5];
  const float* bk    = (const float*)d_in[6];
  const float* wv    = (const float*)d_in[7];
  const float* bv    = (const float*)d_in[8];
  const float* wp    = (const float*)d_in[9];
  const float* bp    = (const float*)d_in[10];
  float* out = (float*)d_out;

  const size_t per = (size_t)BATCH * CDIM * NPIX;  // 4,194,304
  char* ws = (char*)d_ws;
  // opart: B*KS=8 partials fp16 [pair][chan][row] = 32MB. h (fp32 16.8MB) aliases it.
  unsigned short* opart = (unsigned short*)ws;
  float* h = (float*)ws;
  unsigned short* qbuf = (unsigned short*)(ws + (size_t)BATCH * KS * CDIM * NPIX * 2);
  unsigned short* kbuf = qbuf + per;
  unsigned short* vbuf = kbuf + per;
  float* mlbuf = (float*)(vbuf + per);                   // 8*4096*2 fp32 = 0.25MB
  float* wn    = mlbuf + (size_t)BATCH * KS * NPIX * 2;  // 8*4096 fp32 = 0.13MB
  float* ao    = (float*)qbuf;                           // q+k dead after attn (16.8MB)

  gn_kernel<<<dim3(BATCH * NGROUP), dim3(1024), 0, stream>>>(x, gamma, beta, h);
  dim3 cgrid(NPIX / 64, CDIM / 64, BATCH);
  conv1x1_kernel<1><<<cgrid, 256, 0, stream>>>(wq, bq, h, nullptr, nullptr, qbuf);
  conv1x1_kernel<1><<<cgrid, 256, 0, stream>>>(wk, bk, h, nullptr, nullptr, kbuf);
  conv1x1_kernel<2><<<cgrid, 256, 0, stream>>>(wv, bv, h, nullptr, nullptr, vbuf);
  attn_kernel<<<dim3((NPIX / QT) * BATCH * KS), 256, 0, stream>>>(qbuf, kbuf, vbuf, opart, mlbuf);
  wn_kernel<<<dim3(BATCH * NPIX / 256), 256, 0, stream>>>(mlbuf, wn);
  combine_kernel<<<dim3((unsigned)(per / 8 / 256)), 256, 0, stream>>>(opart, wn, ao);
  conv1x1_kernel<0><<<cgrid, 256, 0, stream>>>(wp, bp, ao, x, out, nullptr);
}